// Round 18
// baseline (300.642 us; speedup 1.0000x reference)
//
#include <hip/hip_runtime.h>

#define TT 8192
#define CC 1024
#define HD 64
#define TAIL0 (TT - 64)
#define IMP_OFF ((size_t)TT * HD)
#define CK_OFF (IMP_OFF + (size_t)(TT - 1) * TT)
#define CV_OFF (CK_OFF + (size_t)(TT - 1) * HD)

typedef float f32x4 __attribute__((ext_vector_type(4)));
typedef short short8 __attribute__((ext_vector_type(8)));

static __device__ __forceinline__ short f2bf(float f) {
  union { float f; unsigned u; } v; v.f = f;
  unsigned u = v.u;
  unsigned r = (u + 0x7fffu + ((u >> 16) & 1u)) >> 16;  // RNE
  return (short)r;
}
static __device__ __forceinline__ float bf2f(short h) {
  union { unsigned u; float f; } v;
  v.u = ((unsigned)(unsigned short)h) << 16;
  return v.f;
}
static __device__ __forceinline__ f32x4 mfma16(short8 a, short8 b, f32x4 c) {
  return __builtin_amdgcn_mfma_f32_16x16x32_bf16(a, b, c, 0, 0, 0);
}
static __device__ __forceinline__ void nt_store4(float* p, f32x4 v) {
  __builtin_nontemporal_store(v, (f32x4*)p);
}

// ---- K1: prep: wt build + colsums zero + rope tables + out zero -------------
__global__ void prep(const float* __restrict__ Wk, const float* __restrict__ Wq,
                     const float* __restrict__ Wv, short* __restrict__ wth,
                     short* __restrict__ wtl, float* __restrict__ colsums,
                     float* __restrict__ ctab, float* __restrict__ stab,
                     float* __restrict__ outp) {
  const int b = blockIdx.x;
  if (b < 768) {
    const int tid = b * 256 + threadIdx.x;
    const int col = tid >> 10, c = tid & 1023;
    const int m = col >> 6, d = col & 63;
    const float* W = (m == 0) ? Wk : (m == 1) ? Wq : Wv;
    const float w = W[c * HD + d];
    const short h = f2bf(w);
    wth[col * CC + c] = h;
    wtl[col * CC + c] = f2bf(w - bf2f(h));
  } else if (b < 800) {
    const int t = (b - 768) * 256 + threadIdx.x;   // 0..8191
    colsums[t] = 0.0f;
  } else if (b < 1824) {
    const int t = (b - 800) * 256 + threadIdx.x;   // 0..262143
    const int row = t >> 5, fi = t & 31;
    const float inv = (float)(1.0 / pow(10000.0, (double)fi / 32.0));
    const float ang = (float)row * inv;            // f32, matches reference
    float sn, cs;
    sincosf(ang, &sn, &cs);
    ctab[t] = cs; stab[t] = sn;
  } else {
    const int t = (b - 1824) * 256 + threadIdx.x;  // 0..TT*HD-1
    outp[t] = 0.0f;
  }
}

// ---- K2: fused QKV GEMM (split-bf16, 3xMFMA) + RoPE (table lookup) ----------
__global__ __launch_bounds__(256) void qkv_rope(
    const float* __restrict__ x, const short* __restrict__ wth,
    const short* __restrict__ wtl, const float* __restrict__ ctab,
    const float* __restrict__ stab,
    short* __restrict__ qb, short* __restrict__ kb, short* __restrict__ vt,
    float* __restrict__ kf, float* __restrict__ vf, float* __restrict__ qf) {
  __shared__ short xsh[16][1024];
  __shared__ short xsl[16][1024];
  const int tid = threadIdx.x;
  const int lane = tid & 63, wv = tid >> 6;
  const int g = lane >> 4, lr = lane & 15, g8 = g * 8;
  const int r0 = blockIdx.x * 16;

  for (int i = tid; i < 16 * 128; i += 256) {
    const int row = i >> 7, u = i & 127;
    const float4 a4 = *(const float4*)&x[(size_t)(r0 + row) * CC + u * 8];
    const float4 b4 = *(const float4*)&x[(size_t)(r0 + row) * CC + u * 8 + 4];
    const float xv[8] = {a4.x, a4.y, a4.z, a4.w, b4.x, b4.y, b4.z, b4.w};
    short8 h, l;
#pragma unroll
    for (int t = 0; t < 8; ++t) {
      h[t] = f2bf(xv[t]);
      l[t] = f2bf(xv[t] - bf2f(h[t]));
    }
    const int us = (u ^ (row & 7)) * 8;
    *(short8*)&xsh[row][us] = h;
    *(short8*)&xsl[row][us] = l;
  }
  __syncthreads();

  const int ct0 = wv * 3;
  f32x4 acc[3];
#pragma unroll
  for (int i = 0; i < 3; ++i) acc[i] = (f32x4){0.f, 0.f, 0.f, 0.f};
  for (int kc = 0; kc < 32; ++kc) {
    const int us = ((kc * 4 + g) ^ (lr & 7)) * 8;
    const short8 ah = *(const short8*)&xsh[lr][us];
    const short8 al = *(const short8*)&xsl[lr][us];
    const int k0 = kc * 32 + g8;
#pragma unroll
    for (int t = 0; t < 3; ++t) {
      const int ct = ct0 + t;
      const short8 bh = *(const short8*)&wth[(ct * 16 + lr) * CC + k0];
      const short8 bl = *(const short8*)&wtl[(ct * 16 + lr) * CC + k0];
      acc[t] = mfma16(ah, bh, acc[t]);
      acc[t] = mfma16(al, bh, acc[t]);
      acc[t] = mfma16(ah, bl, acc[t]);
    }
  }
#pragma unroll
  for (int t = 0; t < 3; ++t) {
    const int col = ct0 * 16 + t * 16 + lr;
    const int m = col >> 6, d = col & 63;
#pragma unroll
    for (int r = 0; r < 4; ++r) {
      const int row = r0 + g * 4 + r;
      const float val = acc[t][r];
      if (m == 2) {
        vf[row * HD + d] = val;
        vt[(size_t)d * TT + row] = f2bf(val);
      } else {
        const float partner = __shfl_xor(val, 1);
        const int fi = d >> 1;
        const float cs = ctab[row * 32 + fi];
        const float sn = stab[row * 32 + fi];
        const float res = (d & 1) ? (partner * sn + val * cs)
                                  : (val * cs - partner * sn);
        if (m == 0) { kf[row * HD + d] = res; kb[row * HD + d] = f2bf(res); }
        else        { qf[row * HD + d] = res; qb[row * HD + d] = f2bf(res); }
      }
    }
  }
}

// ---- K3: softmax denominators, 1-wave blocks, grid (512, 8) -----------------
__global__ __launch_bounds__(64) void lpass(
    const short* __restrict__ qb, const short* __restrict__ kb,
    float* __restrict__ l_part) {
  const int lane = threadIdx.x & 63;
  const int g = lane >> 4, lr = lane & 15, g8 = g * 8;
  const int rt = (int)gridDim.x - 1 - (int)blockIdx.x;  // heavy first
  const int cc = blockIdx.y;
  const int r0 = rt * 16, rmax = r0 + 15, c0 = cc * 1024;
  float* lp = l_part + (size_t)cc * TT;
  if (c0 > rmax) { if (lane < 16) lp[r0 + lane] = 0.0f; return; }
  const short8 a0 = *(const short8*)&qb[(r0 + lr) * HD + g8];
  const short8 a1 = *(const short8*)&qb[(r0 + lr) * HD + 32 + g8];
  float lacc[4] = {0.f, 0.f, 0.f, 0.f};
  const int nkt = min(64, (rmax - c0) / 16 + 1);
  for (int kt = 0; kt < nkt; ++kt) {
    const int j0 = c0 + kt * 16;
    const short8 b0 = *(const short8*)&kb[(j0 + lr) * HD + g8];
    const short8 b1 = *(const short8*)&kb[(j0 + lr) * HD + 32 + g8];
    f32x4 sv = (f32x4){0.f, 0.f, 0.f, 0.f};
    sv = mfma16(a0, b0, sv);
    sv = mfma16(a1, b1, sv);
    const int j = j0 + lr;
#pragma unroll
    for (int r = 0; r < 4; ++r) {
      const int i = r0 + g * 4 + r;
      if (j <= i) lacc[r] += __expf(sv[r] * 0.125f);
    }
  }
#pragma unroll
  for (int r = 0; r < 4; ++r) {
#pragma unroll
    for (int m = 1; m < 16; m <<= 1) lacc[r] += __shfl_xor(lacc[r], m);
  }
  if (lr == 0) {
#pragma unroll
    for (int r = 0; r < 4; ++r) lp[r0 + g * 4 + r] = lacc[r];
  }
}

__global__ void linv_k(const float* __restrict__ l_part, float* __restrict__ linv) {
  const int i = blockIdx.x * 256 + threadIdx.x;
  if (i >= TT) return;
  float s = 0.f;
#pragma unroll
  for (int cc = 0; cc < 8; ++cc) s += l_part[(size_t)cc * TT + i];
  linv[i] = 1.0f / s;
}

// ---- K4: pass B only, grid (512 stripes x 2 col-halves) x 512 thr -----------
//          wei->imp (NT) + colsums + PV; tree-combine + atomicAdd out.
__global__ __launch_bounds__(512) void attn_b(
    const short* __restrict__ qb, const short* __restrict__ kb,
    const short* __restrict__ vt, const float* __restrict__ linv,
    float* __restrict__ colsums, float* __restrict__ outp,
    float* __restrict__ stash) {
  const int tid = threadIdx.x;
  const int lane = tid & 63, wv = tid >> 6;
  const int g = lane >> 4, lr = lane & 15, g8 = g * 8;
  const int bid = (int)blockIdx.x;
  const int h2 = (int)blockIdx.y;
  const int rt = (bid < 256) ? (511 - bid) : (bid - 256);
  const int r0 = rt * 16, rmax = r0 + 15;
  const int nkt = rt + 1;
  const int nktp = (nkt + 1) >> 1;
  float* imp = outp + IMP_OFF;
  const f32x4 z4 = (f32x4){0.f, 0.f, 0.f, 0.f};

  __shared__ float et[8][16][36];

  const short8 a0 = *(const short8*)&qb[(r0 + lr) * HD + g8];
  const short8 a1 = *(const short8*)&qb[(r0 + lr) * HD + 32 + g8];
  float rinv[4];
#pragma unroll
  for (int r = 0; r < 4; ++r) rinv[r] = linv[r0 + g * 4 + r];

  f32x4 oacc[4];
#pragma unroll
  for (int ct = 0; ct < 4; ++ct) oacc[ct] = z4;
  const int worow = lane >> 3, wof4 = (lane & 7) * 4;
  for (int kp = wv + 8 * h2; kp < nktp; kp += 16) {
    const int j0p = kp * 32;
    short8 bv[4];
#pragma unroll
    for (int ct = 0; ct < 4; ++ct)
      bv[ct] = *(const short8*)&vt[(size_t)(ct * 16 + lr) * TT + j0p + g8];
#pragma unroll
    for (int h = 0; h < 2; ++h) {
      const int j0 = j0p + h * 16;
      float w4[4] = {0.f, 0.f, 0.f, 0.f};
      if (j0 <= rmax) {
        const short8 b0 = *(const short8*)&kb[(j0 + lr) * HD + g8];
        const short8 b1 = *(const short8*)&kb[(j0 + lr) * HD + 32 + g8];
        f32x4 sv = z4;
        sv = mfma16(a0, b0, sv);
        sv = mfma16(a1, b1, sv);
        const int j = j0 + lr;
#pragma unroll
        for (int r = 0; r < 4; ++r) {
          const int i = r0 + g * 4 + r;
          w4[r] = (j <= i) ? __expf(sv[r] * 0.125f) * rinv[r] : 0.0f;
        }
        float csum = w4[0] + w4[1] + w4[2] + w4[3];
        csum += __shfl_xor(csum, 16);
        csum += __shfl_xor(csum, 32);
        if (lane < 16 && csum > 0.f) atomicAdd(&colsums[j0 + lane], csum);
      }
#pragma unroll
      for (int r = 0; r < 4; ++r) et[wv][g * 4 + r][h * 16 + lr] = w4[r];
    }
    const float4 e0 = *(const float4*)&et[wv][lr][g8];
    const float4 e1 = *(const float4*)&et[wv][lr][g8 + 4];
    short8 ea;
    ea[0] = f2bf(e0.x); ea[1] = f2bf(e0.y); ea[2] = f2bf(e0.z); ea[3] = f2bf(e0.w);
    ea[4] = f2bf(e1.x); ea[5] = f2bf(e1.y); ea[6] = f2bf(e1.z); ea[7] = f2bf(e1.w);
#pragma unroll
    for (int ct = 0; ct < 4; ++ct) oacc[ct] = mfma16(ea, bv[ct], oacc[ct]);
#pragma unroll
    for (int p = 0; p < 2; ++p) {
      const int row = p * 8 + worow;
      const int i = r0 + row;
      const f32x4 v = *(const f32x4*)&et[wv][row][wof4];
      if (i < TT - 1) nt_store4(&imp[(size_t)i * TT + j0p + wof4], v);
      else            *(f32x4*)&stash[j0p + wof4] = v;
    }
  }
  // zero-fill masked columns [nktp*32, TT), interleaved across halves
  const int zstart = nktp * 32;
  for (int row = 0; row < 16; ++row) {
    const int i = r0 + row;
    if (i < TT - 1) {
      float* dst = &imp[(size_t)i * TT];
      for (int c = zstart + (tid + h2 * 512) * 4; c < TT; c += 4096)
        nt_store4(&dst[c], z4);
    } else {
      for (int c = zstart + (tid + h2 * 512) * 4; c < TT; c += 4096)
        *(f32x4*)&stash[c] = z4;
    }
  }
  // tree-combine 8 waves' PV partials through et, then atomicAdd to out
  __syncthreads();
  float* cbuf = &et[0][0][0];
#pragma unroll
  for (int step = 4; step >= 1; step >>= 1) {
    if (wv >= step && wv < 2 * step) {
      float* dst = cbuf + (size_t)(wv - step) * 1024;
#pragma unroll
      for (int ct = 0; ct < 4; ++ct)
#pragma unroll
        for (int r = 0; r < 4; ++r)
          dst[(g * 4 + r) * 64 + ct * 16 + lr] = oacc[ct][r];
    }
    __syncthreads();
    if (wv < step) {
      const float* src = cbuf + (size_t)wv * 1024;
#pragma unroll
      for (int ct = 0; ct < 4; ++ct)
#pragma unroll
        for (int r = 0; r < 4; ++r)
          oacc[ct][r] += src[(g * 4 + r) * 64 + ct * 16 + lr];
    }
    __syncthreads();
  }
  if (wv == 0) {
#pragma unroll
    for (int ct = 0; ct < 4; ++ct)
#pragma unroll
      for (int r = 0; r < 4; ++r)
        atomicAdd(&outp[(size_t)(r0 + g * 4 + r) * HD + ct * 16 + lr], oacc[ct][r]);
  }
}

// ---- K5: exact f32 tail rows ------------------------------------------------
__global__ __launch_bounds__(256) void tail_exact(
    const float* __restrict__ qf, const float* __restrict__ kf,
    float* __restrict__ l_exact, float* __restrict__ tail_e) {
  const int b = blockIdx.x;
  const int i = TAIL0 + b;
  const int tid = threadIdx.x;
  __shared__ float qs[64];
  __shared__ float ws4[4];
  if (tid < 64) {
    qs[tid] = qf[i * HD + tid];
    if (TAIL0 + tid > i) tail_e[(b << 6) + tid] = 0.0f;
  }
  __syncthreads();
  float part = 0.f;
  for (int j = tid; j <= i; j += 256) {
    const float* kr = &kf[(size_t)j * HD];
    float dot = 0.f;
#pragma unroll
    for (int d = 0; d < 64; ++d) dot += qs[d] * kr[d];
    const float e = expf(dot * 0.125f);
    part += e;
    if (j >= TAIL0) tail_e[(b << 6) + (j - TAIL0)] = e;
  }
#pragma unroll
  for (int m = 1; m < 64; m <<= 1) part += __shfl_xor(part, m);
  if ((tid & 63) == 0) ws4[tid >> 6] = part;
  __syncthreads();
  if (tid == 0) l_exact[b] = ws4[0] + ws4[1] + ws4[2] + ws4[3];
}

// ---- K6: argmin (exact tail cols, coarse below) ------------------------------
__global__ void argmin_k(const float* __restrict__ colsums,
                         const float* __restrict__ l_exact,
                         const float* __restrict__ tail_e,
                         int* __restrict__ evict) {
  __shared__ float sv[4];
  __shared__ int si[4];
  const int tid = threadIdx.x, lane = tid & 63, wv = tid >> 6;
  float best = 3.4e38f; int bi = TT;
  for (int j = tid; j < TT; j += 256) {
    float v;
    if (j >= TAIL0) {
      const int jc = j - TAIL0;
      v = 0.f;
      for (int b = jc; b < 64; ++b) v += tail_e[(b << 6) + jc] / l_exact[b];
    } else {
      v = colsums[j];
    }
    if (v < best) { best = v; bi = j; }
  }
#pragma unroll
  for (int m = 1; m < 64; m <<= 1) {
    const float ov = __shfl_xor(best, m);
    const int oi = __shfl_xor(bi, m);
    if (ov < best || (ov == best && oi < bi)) { best = ov; bi = oi; }
  }
  if (lane == 0) { sv[wv] = best; si[wv] = bi; }
  __syncthreads();
  if (tid == 0) {
    for (int w = 1; w < 4; ++w)
      if (sv[w] < best || (sv[w] == best && si[w] < bi)) { best = sv[w]; bi = si[w]; }
    evict[0] = bi;
  }
}

// ---- K7: fix rows [eid..TT-2] (recompute/stash) + cache_k/v write -----------
__global__ __launch_bounds__(256) void fix_cache(
    const float* __restrict__ qf, const float* __restrict__ kf,
    const float* __restrict__ vf, const float* __restrict__ linv,
    const float* __restrict__ stash, const int* __restrict__ evict,
    float* __restrict__ outp) {
  const int bid = (int)blockIdx.x;
  const int tid = threadIdx.x;
  const int eid = evict[0];
  if (bid < 512) {
    float* imp = outp + IMP_OFF;
    __shared__ float qs[64];
    for (int dst = eid + bid; dst < TT - 1; dst += 512) {
      const int src = dst + 1;
      if (src == TT - 1) {
        for (int c = tid; c < TT / 4; c += 256)
          ((f32x4*)&imp[(size_t)dst * TT])[c] = ((const f32x4*)stash)[c];
      } else {
        if (tid < 64) qs[tid] = qf[src * HD + tid];
        __syncthreads();
        const float rinv = linv[src];
        for (int j = tid; j < TT; j += 256) {
          float w = 0.f;
          if (j <= src) {
            const float* kr = &kf[(size_t)j * HD];
            float dot = 0.f;
#pragma unroll
            for (int d = 0; d < 64; ++d) dot += qs[d] * kr[d];
            w = expf(dot * 0.125f) * rinv;
          }
          imp[(size_t)dst * TT + j] = w;
        }
        __syncthreads();
      }
    }
  } else {
    const int t = (bid - 512) * 256 + tid;
    const int per = (TT - 1) * (HD / 4);
    if (t >= 2 * per) return;
    const int m = t / per;
    const int rem = t - m * per;
    const int r = rem >> 4, c4 = rem & 15;
    const int src = r + (r >= eid);
    const float* sp = m ? vf : kf;
    const f32x4 val = *(const f32x4*)&sp[src * HD + c4 * 4];
    float* dst = outp + (m ? CV_OFF : CK_OFF);
    nt_store4(&dst[r * HD + c4 * 4], val);
  }
}

extern "C" void kernel_launch(void* const* d_in, const int* in_sizes, int n_in,
                              void* d_out, int out_size, void* d_ws, size_t ws_size,
                              hipStream_t stream) {
  const float* x  = (const float*)d_in[0];
  const float* Wk = (const float*)d_in[1];
  const float* Wq = (const float*)d_in[2];
  const float* Wv = (const float*)d_in[3];
  float* outp = (float*)d_out;
  char* ws = (char*)d_ws;
  short* qb      = (short*)(ws);                        // 1 MB
  short* kb      = (short*)(ws + (1u << 20));           // 1 MB
  short* vt      = (short*)(ws + (2u << 20));           // 1 MB
  float* kf      = (float*)(ws + (3u << 20));           // 2 MB
  float* vf      = (float*)(ws + (5u << 20));           // 2 MB
  float* qf      = (float*)(ws + (7u << 20));           // 2 MB
  float* linv    = (float*)(ws + (9u << 20));           // 32 KB
  int*   evict   = (int*)  (ws + (9u << 20) + (64u << 10));   // 4 B
  float* l_part  = (float*)(ws + (9u << 20) + (128u << 10));  // 256 KB
  float* colsums = (float*)(ws + (9u << 20) + (384u << 10));  // 32 KB
  short* wth     = (short*)(ws + (9u << 20) + (448u << 10));  // 384 KB
  short* wtl     = (short*)(ws + (9u << 20) + (832u << 10));  // 384 KB
  float* tail_e  = (float*)(ws + (9u << 20) + (1280u << 10)); // 16 KB
  float* l_exact = (float*)(ws + (9u << 20) + (1344u << 10)); // 256 B
  float* stash   = (float*)(ws + (9u << 20) + (1408u << 10)); // 32 KB
  float* ctab    = (float*)(ws + (12u << 20));          // 1 MB
  float* stab    = (float*)(ws + (13u << 20));          // 1 MB

  prep<<<3872, 256, 0, stream>>>(Wk, Wq, Wv, wth, wtl, colsums, ctab, stab, outp);
  qkv_rope<<<512, 256, 0, stream>>>(x, wth, wtl, ctab, stab, qb, kb, vt, kf, vf, qf);
  lpass<<<dim3(512, 8), 64, 0, stream>>>(qb, kb, l_part);
  linv_k<<<32, 256, 0, stream>>>(l_part, linv);
  attn_b<<<dim3(512, 2), 512, 0, stream>>>(qb, kb, vt, linv, colsums, outp, stash);
  tail_exact<<<64, 256, 0, stream>>>(qf, kf, l_exact, tail_e);
  argmin_k<<<1, 256, 0, stream>>>(colsums, l_exact, tail_e, evict);
  fix_cache<<<1536, 256, 0, stream>>>(qf, kf, vf, linv, stash, evict, outp);
}

// Round 19
// 231.805 us; speedup vs baseline: 1.2970x; 1.2970x over previous
//
#include <hip/hip_runtime.h>

#define TT 8192
#define CC 1024
#define HD 64
#define TAIL0 (TT - 64)
#define IMP_OFF ((size_t)TT * HD)
#define CK_OFF (IMP_OFF + (size_t)(TT - 1) * TT)
#define CV_OFF (CK_OFF + (size_t)(TT - 1) * HD)

typedef float f32x4 __attribute__((ext_vector_type(4)));
typedef short short8 __attribute__((ext_vector_type(8)));

static __device__ __forceinline__ short f2bf(float f) {
  union { float f; unsigned u; } v; v.f = f;
  unsigned u = v.u;
  unsigned r = (u + 0x7fffu + ((u >> 16) & 1u)) >> 16;  // RNE
  return (short)r;
}
static __device__ __forceinline__ float bf2f(short h) {
  union { unsigned u; float f; } v;
  v.u = ((unsigned)(unsigned short)h) << 16;
  return v.f;
}
static __device__ __forceinline__ f32x4 mfma16(short8 a, short8 b, f32x4 c) {
  return __builtin_amdgcn_mfma_f32_16x16x32_bf16(a, b, c, 0, 0, 0);
}
static __device__ __forceinline__ void nt_store4(float* p, f32x4 v) {
  __builtin_nontemporal_store(v, (f32x4*)p);
}

// ---- K1: prep: wt build + colsums zero + rope cos/sin tables ----------------
__global__ void prep(const float* __restrict__ Wk, const float* __restrict__ Wq,
                     const float* __restrict__ Wv, short* __restrict__ wth,
                     short* __restrict__ wtl, float* __restrict__ colsums,
                     float* __restrict__ ctab, float* __restrict__ stab) {
  const int b = blockIdx.x;
  if (b < 768) {
    const int tid = b * 256 + threadIdx.x;
    const int col = tid >> 10, c = tid & 1023;
    const int m = col >> 6, d = col & 63;
    const float* W = (m == 0) ? Wk : (m == 1) ? Wq : Wv;
    const float w = W[c * HD + d];
    const short h = f2bf(w);
    wth[col * CC + c] = h;
    wtl[col * CC + c] = f2bf(w - bf2f(h));
  } else if (b < 800) {
    const int t = (b - 768) * 256 + threadIdx.x;   // 0..8191
    colsums[t] = 0.0f;
  } else {
    const int t = (b - 800) * 256 + threadIdx.x;   // 0..262143
    const int row = t >> 5, fi = t & 31;
    const float inv = (float)(1.0 / pow(10000.0, (double)fi / 32.0));
    const float ang = (float)row * inv;            // f32, matches reference
    float sn, cs;
    sincosf(ang, &sn, &cs);
    ctab[t] = cs; stab[t] = sn;
  }
}

// ---- K2: fused QKV GEMM (split-bf16, 3xMFMA) + RoPE; K/V to blocked
//          MFMA-fragment layouts (kbb: [kt][h][lane]x8, vbb: [kp][ct][lane]x8)
__global__ __launch_bounds__(256) void qkv_rope(
    const float* __restrict__ x, const short* __restrict__ wth,
    const short* __restrict__ wtl, const float* __restrict__ ctab,
    const float* __restrict__ stab,
    short* __restrict__ qb, short* __restrict__ kbb, short* __restrict__ vbb,
    float* __restrict__ kf, float* __restrict__ vf, float* __restrict__ qf) {
  __shared__ short xsh[16][1024];
  __shared__ short xsl[16][1024];
  const int tid = threadIdx.x;
  const int lane = tid & 63, wv = tid >> 6;
  const int g = lane >> 4, lr = lane & 15, g8 = g * 8;
  const int r0 = blockIdx.x * 16;

  for (int i = tid; i < 16 * 128; i += 256) {
    const int row = i >> 7, u = i & 127;
    const float4 a4 = *(const float4*)&x[(size_t)(r0 + row) * CC + u * 8];
    const float4 b4 = *(const float4*)&x[(size_t)(r0 + row) * CC + u * 8 + 4];
    const float xv[8] = {a4.x, a4.y, a4.z, a4.w, b4.x, b4.y, b4.z, b4.w};
    short8 h, l;
#pragma unroll
    for (int t = 0; t < 8; ++t) {
      h[t] = f2bf(xv[t]);
      l[t] = f2bf(xv[t] - bf2f(h[t]));
    }
    const int us = (u ^ (row & 7)) * 8;
    *(short8*)&xsh[row][us] = h;
    *(short8*)&xsl[row][us] = l;
  }
  __syncthreads();

  const int ct0 = wv * 3;
  f32x4 acc[3];
#pragma unroll
  for (int i = 0; i < 3; ++i) acc[i] = (f32x4){0.f, 0.f, 0.f, 0.f};
  for (int kc = 0; kc < 32; ++kc) {
    const int us = ((kc * 4 + g) ^ (lr & 7)) * 8;
    const short8 ah = *(const short8*)&xsh[lr][us];
    const short8 al = *(const short8*)&xsl[lr][us];
    const int k0 = kc * 32 + g8;
#pragma unroll
    for (int t = 0; t < 3; ++t) {
      const int ct = ct0 + t;
      const short8 bh = *(const short8*)&wth[(ct * 16 + lr) * CC + k0];
      const short8 bl = *(const short8*)&wtl[(ct * 16 + lr) * CC + k0];
      acc[t] = mfma16(ah, bh, acc[t]);
      acc[t] = mfma16(al, bh, acc[t]);
      acc[t] = mfma16(ah, bl, acc[t]);
    }
  }
#pragma unroll
  for (int t = 0; t < 3; ++t) {
    const int col = ct0 * 16 + t * 16 + lr;
    const int m = col >> 6, d = col & 63;
#pragma unroll
    for (int r = 0; r < 4; ++r) {
      const int row = r0 + g * 4 + r;
      const float val = acc[t][r];
      if (m == 2) {                 // V: no rope; vf + blocked vbb
        vf[row * HD + d] = val;
        const int kp = row >> 5, r32 = row & 31;
        const int gv = r32 >> 3, tv = r32 & 7;
        const int ctv = d >> 4, lrv = d & 15;
        vbb[kp * 2048 + ctv * 512 + gv * 128 + lrv * 8 + tv] = f2bf(val);
      } else {                       // K or Q: rope via table
        const float partner = __shfl_xor(val, 1);
        const int fi = d >> 1;
        const float cs = ctab[row * 32 + fi];
        const float sn = stab[row * 32 + fi];
        const float res = (d & 1) ? (partner * sn + val * cs)
                                  : (val * cs - partner * sn);
        if (m == 0) {
          kf[row * HD + d] = res;
          const int kt = row >> 4, lrk = row & 15;
          const int hh = d >> 5, gk = (d & 31) >> 3, tk = d & 7;
          kbb[kt * 1024 + hh * 512 + gk * 128 + lrk * 8 + tk] = f2bf(res);
        } else {
          qf[row * HD + d] = res;
          qb[row * HD + d] = f2bf(res);
        }
      }
    }
  }
}

// ---- K3: attention, 8 waves/block, grid 512; 2-chain ILP + NT stores +
//          fully-coalesced blocked K/V loads --------------------------------
__global__ __launch_bounds__(512) void attn_row(
    const short* __restrict__ qb, const short* __restrict__ kbb,
    const short* __restrict__ vbb, float* __restrict__ colsums,
    float* __restrict__ outp, float* __restrict__ stash,
    float* __restrict__ linv_g) {
  const int tid = threadIdx.x;
  const int lane = tid & 63, wv = tid >> 6;
  const int g = lane >> 4, lr = lane & 15, g8 = g * 8;
  const int bid = (int)blockIdx.x;
  const int rt = (bid < 256) ? (511 - bid) : (bid - 256);
  const int r0 = rt * 16, rmax = r0 + 15;
  const int nkt = rt + 1;
  const int nktp = (nkt + 1) >> 1;
  float* imp = outp + IMP_OFF;
  const f32x4 z4 = (f32x4){0.f, 0.f, 0.f, 0.f};

  __shared__ float et[8][16][36];
  __shared__ float et2[8][16][36];
  __shared__ float l4[8][16];

  const short8 a0 = *(const short8*)&qb[(r0 + lr) * HD + g8];
  const short8 a1 = *(const short8*)&qb[(r0 + lr) * HD + 32 + g8];
  const int ln8 = lane * 8;

  // ---- pass A: denominators, 2 chains per iteration (coalesced kbb loads)
  float lacc[4] = {0.f, 0.f, 0.f, 0.f};
  for (int kt = wv; kt < nkt; kt += 16) {
    const int ktb = kt + 8;
    const bool has1 = (ktb < nkt);
    const short8 b00 = *(const short8*)&kbb[kt * 1024 + ln8];
    const short8 b01 = *(const short8*)&kbb[kt * 1024 + 512 + ln8];
    short8 b10, b11;
    if (has1) {
      b10 = *(const short8*)&kbb[ktb * 1024 + ln8];
      b11 = *(const short8*)&kbb[ktb * 1024 + 512 + ln8];
    }
    f32x4 sv0 = z4;
    sv0 = mfma16(a0, b00, sv0);
    sv0 = mfma16(a1, b01, sv0);
    f32x4 sv1 = z4;
    if (has1) {
      sv1 = mfma16(a0, b10, sv1);
      sv1 = mfma16(a1, b11, sv1);
    }
    const int jj0 = kt * 16 + lr, jj1 = ktb * 16 + lr;
#pragma unroll
    for (int r = 0; r < 4; ++r) {
      const int i = r0 + g * 4 + r;
      if (jj0 <= i) lacc[r] += __expf(sv0[r] * 0.125f);
      if (has1 && jj1 <= i) lacc[r] += __expf(sv1[r] * 0.125f);
    }
  }
#pragma unroll
  for (int r = 0; r < 4; ++r) {
#pragma unroll
    for (int m = 1; m < 16; m <<= 1) lacc[r] += __shfl_xor(lacc[r], m);
  }
  if (lr == 0) {
#pragma unroll
    for (int r = 0; r < 4; ++r) l4[wv][g * 4 + r] = lacc[r];
  }
  __syncthreads();
  float rinv[4];
#pragma unroll
  for (int r = 0; r < 4; ++r) {
    const int row = g * 4 + r;
    float s = 0.f;
#pragma unroll
    for (int w = 0; w < 8; ++w) s += l4[w][row];
    rinv[r] = 1.0f / s;
  }
  if (wv == 0 && lr == 0) {
#pragma unroll
    for (int r = 0; r < 4; ++r) linv_g[r0 + g * 4 + r] = rinv[r];
  }

  // ---- pass B: 2 chains per iteration; wei->imp (NT) + colsums + PV
  f32x4 oacc[4], oacc2[4];
#pragma unroll
  for (int ct = 0; ct < 4; ++ct) { oacc[ct] = z4; oacc2[ct] = z4; }
  const int worow = lane >> 3, wof4 = (lane & 7) * 4;
  for (int kp = wv; kp < nktp; kp += 16) {
    const int kpb = kp + 8;
    const bool has1 = (kpb < nktp);
    const int j0p0 = kp * 32, j0p1 = kpb * 32;
    // coalesced V tile loads for both chains
    short8 bv0[4], bv1[4];
#pragma unroll
    for (int ct = 0; ct < 4; ++ct)
      bv0[ct] = *(const short8*)&vbb[kp * 2048 + ct * 512 + ln8];
    if (has1) {
#pragma unroll
      for (int ct = 0; ct < 4; ++ct)
        bv1[ct] = *(const short8*)&vbb[kpb * 2048 + ct * 512 + ln8];
    }
#pragma unroll
    for (int c = 0; c < 2; ++c) {
      if (c == 1 && !has1) break;
      const int j0p = c ? j0p1 : j0p0;
      float (*etp)[36] = c ? et2[wv] : et[wv];
#pragma unroll
      for (int h = 0; h < 2; ++h) {
        const int kt = (c ? kpb : kp) * 2 + h;
        const int j0 = j0p + h * 16;
        float w4[4] = {0.f, 0.f, 0.f, 0.f};
        if (j0 <= rmax) {
          const short8 b0 = *(const short8*)&kbb[kt * 1024 + ln8];
          const short8 b1 = *(const short8*)&kbb[kt * 1024 + 512 + ln8];
          f32x4 sv = z4;
          sv = mfma16(a0, b0, sv);
          sv = mfma16(a1, b1, sv);
          const int j = j0 + lr;
#pragma unroll
          for (int r = 0; r < 4; ++r) {
            const int i = r0 + g * 4 + r;
            w4[r] = (j <= i) ? __expf(sv[r] * 0.125f) * rinv[r] : 0.0f;
          }
          float csum = w4[0] + w4[1] + w4[2] + w4[3];
          csum += __shfl_xor(csum, 16);
          csum += __shfl_xor(csum, 32);
          if (lane < 16 && csum > 0.f) atomicAdd(&colsums[j0 + lane], csum);
        }
#pragma unroll
        for (int r = 0; r < 4; ++r) etp[g * 4 + r][h * 16 + lr] = w4[r];
      }
    }
    // PV chain 0
    {
      const float4 e0 = *(const float4*)&et[wv][lr][g8];
      const float4 e1 = *(const float4*)&et[wv][lr][g8 + 4];
      short8 ea;
      ea[0] = f2bf(e0.x); ea[1] = f2bf(e0.y); ea[2] = f2bf(e0.z); ea[3] = f2bf(e0.w);
      ea[4] = f2bf(e1.x); ea[5] = f2bf(e1.y); ea[6] = f2bf(e1.z); ea[7] = f2bf(e1.w);
#pragma unroll
      for (int ct = 0; ct < 4; ++ct) oacc[ct] = mfma16(ea, bv0[ct], oacc[ct]);
    }
    // PV chain 1
    if (has1) {
      const float4 e0 = *(const float4*)&et2[wv][lr][g8];
      const float4 e1 = *(const float4*)&et2[wv][lr][g8 + 4];
      short8 ea;
      ea[0] = f2bf(e0.x); ea[1] = f2bf(e0.y); ea[2] = f2bf(e0.z); ea[3] = f2bf(e0.w);
      ea[4] = f2bf(e1.x); ea[5] = f2bf(e1.y); ea[6] = f2bf(e1.z); ea[7] = f2bf(e1.w);
#pragma unroll
      for (int ct = 0; ct < 4; ++ct) oacc2[ct] = mfma16(ea, bv1[ct], oacc2[ct]);
    }
    // NT coalesced imp write-out from LDS (both chains)
#pragma unroll
    for (int p = 0; p < 2; ++p) {
      const int row = p * 8 + worow;
      const int i = r0 + row;
      const f32x4 v0 = *(const f32x4*)&et[wv][row][wof4];
      if (i < TT - 1) nt_store4(&imp[(size_t)i * TT + j0p0 + wof4], v0);
      else            *(f32x4*)&stash[j0p0 + wof4] = v0;
      if (has1) {
        const f32x4 v1 = *(const f32x4*)&et2[wv][row][wof4];
        if (i < TT - 1) nt_store4(&imp[(size_t)i * TT + j0p1 + wof4], v1);
        else            *(f32x4*)&stash[j0p1 + wof4] = v1;
      }
    }
  }
  // zero-fill masked columns [nktp*32, TT) with NT stores
  const int zstart = nktp * 32;
  for (int row = 0; row < 16; ++row) {
    const int i = r0 + row;
    if (i < TT - 1) {
      float* dst = &imp[(size_t)i * TT];
      for (int c = zstart + tid * 4; c < TT; c += 2048) nt_store4(&dst[c], z4);
    } else {
      for (int c = zstart + tid * 4; c < TT; c += 2048) *(f32x4*)&stash[c] = z4;
    }
  }
  // merge chain accumulators, tree-combine through et
#pragma unroll
  for (int ct = 0; ct < 4; ++ct)
#pragma unroll
    for (int r = 0; r < 4; ++r) oacc[ct][r] += oacc2[ct][r];
  __syncthreads();
  float* cbuf = &et[0][0][0];
#pragma unroll
  for (int step = 4; step >= 1; step >>= 1) {
    if (wv >= step && wv < 2 * step) {
      float* dst = cbuf + (size_t)(wv - step) * 1024;
#pragma unroll
      for (int ct = 0; ct < 4; ++ct)
#pragma unroll
        for (int r = 0; r < 4; ++r)
          dst[(g * 4 + r) * 64 + ct * 16 + lr] = oacc[ct][r];
    }
    __syncthreads();
    if (wv < step) {
      const float* src = cbuf + (size_t)wv * 1024;
#pragma unroll
      for (int ct = 0; ct < 4; ++ct)
#pragma unroll
        for (int r = 0; r < 4; ++r)
          oacc[ct][r] += src[(g * 4 + r) * 64 + ct * 16 + lr];
    }
    __syncthreads();
  }
  if (wv == 0) {
#pragma unroll
    for (int ct = 0; ct < 4; ++ct)
#pragma unroll
      for (int r = 0; r < 4; ++r)
        outp[(size_t)(r0 + g * 4 + r) * HD + ct * 16 + lr] = oacc[ct][r];
  }
}

// ---- K4: exact f32 tail rows ------------------------------------------------
__global__ __launch_bounds__(256) void tail_exact(
    const float* __restrict__ qf, const float* __restrict__ kf,
    float* __restrict__ l_exact, float* __restrict__ tail_e) {
  const int b = blockIdx.x;
  const int i = TAIL0 + b;
  const int tid = threadIdx.x;
  __shared__ float qs[64];
  __shared__ float ws4[4];
  if (tid < 64) {
    qs[tid] = qf[i * HD + tid];
    if (TAIL0 + tid > i) tail_e[(b << 6) + tid] = 0.0f;
  }
  __syncthreads();
  float part = 0.f;
  for (int j = tid; j <= i; j += 256) {
    const float* kr = &kf[(size_t)j * HD];
    float dot = 0.f;
#pragma unroll
    for (int d = 0; d < 64; ++d) dot += qs[d] * kr[d];
    const float e = expf(dot * 0.125f);
    part += e;
    if (j >= TAIL0) tail_e[(b << 6) + (j - TAIL0)] = e;
  }
#pragma unroll
  for (int m = 1; m < 64; m <<= 1) part += __shfl_xor(part, m);
  if ((tid & 63) == 0) ws4[tid >> 6] = part;
  __syncthreads();
  if (tid == 0) l_exact[b] = ws4[0] + ws4[1] + ws4[2] + ws4[3];
}

// ---- K5: argmin (exact tail cols, coarse below) ------------------------------
__global__ void argmin_k(const float* __restrict__ colsums,
                         const float* __restrict__ l_exact,
                         const float* __restrict__ tail_e,
                         int* __restrict__ evict) {
  __shared__ float sv[4];
  __shared__ int si[4];
  const int tid = threadIdx.x, lane = tid & 63, wv = tid >> 6;
  float best = 3.4e38f; int bi = TT;
  for (int j = tid; j < TT; j += 256) {
    float v;
    if (j >= TAIL0) {
      const int jc = j - TAIL0;
      v = 0.f;
      for (int b = jc; b < 64; ++b) v += tail_e[(b << 6) + jc] / l_exact[b];
    } else {
      v = colsums[j];
    }
    if (v < best) { best = v; bi = j; }
  }
#pragma unroll
  for (int m = 1; m < 64; m <<= 1) {
    const float ov = __shfl_xor(best, m);
    const int oi = __shfl_xor(bi, m);
    if (ov < best || (ov == best && oi < bi)) { best = ov; bi = oi; }
  }
  if (lane == 0) { sv[wv] = best; si[wv] = bi; }
  __syncthreads();
  if (tid == 0) {
    for (int w = 1; w < 4; ++w)
      if (sv[w] < best || (sv[w] == best && si[w] < bi)) { best = sv[w]; bi = si[w]; }
    evict[0] = bi;
  }
}

// ---- K6: fix rows [eid..TT-2] (recompute/stash) + cache_k/v write -----------
__global__ __launch_bounds__(256) void fix_cache(
    const float* __restrict__ qf, const float* __restrict__ kf,
    const float* __restrict__ vf, const float* __restrict__ linv,
    const float* __restrict__ stash, const int* __restrict__ evict,
    float* __restrict__ outp) {
  const int bid = (int)blockIdx.x;
  const int tid = threadIdx.x;
  const int eid = evict[0];
  if (bid < 512) {
    float* imp = outp + IMP_OFF;
    __shared__ float qs[64];
    for (int dst = eid + bid; dst < TT - 1; dst += 512) {
      const int src = dst + 1;
      if (src == TT - 1) {
        for (int c = tid; c < TT / 4; c += 256)
          ((f32x4*)&imp[(size_t)dst * TT])[c] = ((const f32x4*)stash)[c];
      } else {
        if (tid < 64) qs[tid] = qf[src * HD + tid];
        __syncthreads();
        const float rinv = linv[src];
        for (int j = tid; j < TT; j += 256) {
          float w = 0.f;
          if (j <= src) {
            const float* kr = &kf[(size_t)j * HD];
            float dot = 0.f;
#pragma unroll
            for (int d = 0; d < 64; ++d) dot += qs[d] * kr[d];
            w = expf(dot * 0.125f) * rinv;
          }
          imp[(size_t)dst * TT + j] = w;
        }
        __syncthreads();
      }
    }
  } else {
    const int t = (bid - 512) * 256 + tid;
    const int per = (TT - 1) * (HD / 4);
    if (t >= 2 * per) return;
    const int m = t / per;
    const int rem = t - m * per;
    const int r = rem >> 4, c4 = rem & 15;
    const int src = r + (r >= eid);
    const float* sp = m ? vf : kf;
    const f32x4 val = *(const f32x4*)&sp[src * HD + c4 * 4];
    float* dst = outp + (m ? CV_OFF : CK_OFF);
    nt_store4(&dst[r * HD + c4 * 4], val);
  }
}

extern "C" void kernel_launch(void* const* d_in, const int* in_sizes, int n_in,
                              void* d_out, int out_size, void* d_ws, size_t ws_size,
                              hipStream_t stream) {
  const float* x  = (const float*)d_in[0];
  const float* Wk = (const float*)d_in[1];
  const float* Wq = (const float*)d_in[2];
  const float* Wv = (const float*)d_in[3];
  float* outp = (float*)d_out;
  char* ws = (char*)d_ws;
  short* qb      = (short*)(ws);                        // 1 MB
  short* kbb     = (short*)(ws + (1u << 20));           // 1 MB (blocked K)
  short* vbb     = (short*)(ws + (2u << 20));           // 1 MB (blocked V)
  float* kf      = (float*)(ws + (3u << 20));           // 2 MB
  float* vf      = (float*)(ws + (5u << 20));           // 2 MB
  float* qf      = (float*)(ws + (7u << 20));           // 2 MB
  float* linv    = (float*)(ws + (9u << 20));           // 32 KB
  int*   evict   = (int*)  (ws + (9u << 20) + (64u << 10));   // 4 B
  float* colsums = (float*)(ws + (9u << 20) + (384u << 10));  // 32 KB
  short* wth     = (short*)(ws + (9u << 20) + (448u << 10));  // 384 KB
  short* wtl     = (short*)(ws + (9u << 20) + (832u << 10));  // 384 KB
  float* tail_e  = (float*)(ws + (9u << 20) + (1280u << 10)); // 16 KB
  float* l_exact = (float*)(ws + (9u << 20) + (1344u << 10)); // 256 B
  float* stash   = (float*)(ws + (9u << 20) + (1408u << 10)); // 32 KB
  float* ctab    = (float*)(ws + (12u << 20));          // 1 MB
  float* stab    = (float*)(ws + (13u << 20));          // 1 MB

  prep<<<1824, 256, 0, stream>>>(Wk, Wq, Wv, wth, wtl, colsums, ctab, stab);
  qkv_rope<<<512, 256, 0, stream>>>(x, wth, wtl, ctab, stab, qb, kbb, vbb, kf, vf, qf);
  attn_row<<<512, 512, 0, stream>>>(qb, kbb, vbb, colsums, outp, stash, linv);
  tail_exact<<<64, 256, 0, stream>>>(qf, kf, l_exact, tail_e);
  argmin_k<<<1, 256, 0, stream>>>(colsums, l_exact, tail_e, evict);
  fix_cache<<<1536, 256, 0, stream>>>(qf, kf, vf, linv, stash, evict, outp);
}

// Round 20
// 230.307 us; speedup vs baseline: 1.3054x; 1.0065x over previous
//
#include <hip/hip_runtime.h>

#define TT 8192
#define CC 1024
#define HD 64
#define TAIL0 (TT - 64)
#define IMP_OFF ((size_t)TT * HD)
#define CK_OFF (IMP_OFF + (size_t)(TT - 1) * TT)
#define CV_OFF (CK_OFF + (size_t)(TT - 1) * HD)

typedef float f32x4 __attribute__((ext_vector_type(4)));
typedef short short8 __attribute__((ext_vector_type(8)));

static __device__ __forceinline__ short f2bf(float f) {
  union { float f; unsigned u; } v; v.f = f;
  unsigned u = v.u;
  unsigned r = (u + 0x7fffu + ((u >> 16) & 1u)) >> 16;  // RNE
  return (short)r;
}
static __device__ __forceinline__ float bf2f(short h) {
  union { unsigned u; float f; } v;
  v.u = ((unsigned)(unsigned short)h) << 16;
  return v.f;
}
static __device__ __forceinline__ f32x4 mfma16(short8 a, short8 b, f32x4 c) {
  return __builtin_amdgcn_mfma_f32_16x16x32_bf16(a, b, c, 0, 0, 0);
}
static __device__ __forceinline__ void nt_store4(float* p, f32x4 v) {
  __builtin_nontemporal_store(v, (f32x4*)p);
}

// ---- K1: prep: wt build + colsums zero + rope cos/sin tables ----------------
__global__ void prep(const float* __restrict__ Wk, const float* __restrict__ Wq,
                     const float* __restrict__ Wv, short* __restrict__ wth,
                     short* __restrict__ wtl, float* __restrict__ colsums,
                     float* __restrict__ ctab, float* __restrict__ stab) {
  const int b = blockIdx.x;
  if (b < 768) {
    const int tid = b * 256 + threadIdx.x;
    const int col = tid >> 10, c = tid & 1023;
    const int m = col >> 6, d = col & 63;
    const float* W = (m == 0) ? Wk : (m == 1) ? Wq : Wv;
    const float w = W[c * HD + d];
    const short h = f2bf(w);
    wth[col * CC + c] = h;
    wtl[col * CC + c] = f2bf(w - bf2f(h));
  } else if (b < 800) {
    const int t = (b - 768) * 256 + threadIdx.x;   // 0..8191
    colsums[t] = 0.0f;
  } else {
    const int t = (b - 800) * 256 + threadIdx.x;   // 0..262143
    const int row = t >> 5, fi = t & 31;
    const float inv = (float)(1.0 / pow(10000.0, (double)fi / 32.0));
    const float ang = (float)row * inv;            // f32, matches reference
    float sn, cs;
    sincosf(ang, &sn, &cs);
    ctab[t] = cs; stab[t] = sn;
  }
}

// ---- K2: fused QKV GEMM (split-bf16, 3xMFMA) + RoPE; K/V to blocked
//          MFMA-fragment layouts (kbb: [kt][h][lane]x8, vbb: [kp][ct][lane]x8)
__global__ __launch_bounds__(256) void qkv_rope(
    const float* __restrict__ x, const short* __restrict__ wth,
    const short* __restrict__ wtl, const float* __restrict__ ctab,
    const float* __restrict__ stab,
    short* __restrict__ qb, short* __restrict__ kbb, short* __restrict__ vbb,
    float* __restrict__ kf, float* __restrict__ vf, float* __restrict__ qf) {
  __shared__ short xsh[16][1024];
  __shared__ short xsl[16][1024];
  const int tid = threadIdx.x;
  const int lane = tid & 63, wv = tid >> 6;
  const int g = lane >> 4, lr = lane & 15, g8 = g * 8;
  const int r0 = blockIdx.x * 16;

  for (int i = tid; i < 16 * 128; i += 256) {
    const int row = i >> 7, u = i & 127;
    const float4 a4 = *(const float4*)&x[(size_t)(r0 + row) * CC + u * 8];
    const float4 b4 = *(const float4*)&x[(size_t)(r0 + row) * CC + u * 8 + 4];
    const float xv[8] = {a4.x, a4.y, a4.z, a4.w, b4.x, b4.y, b4.z, b4.w};
    short8 h, l;
#pragma unroll
    for (int t = 0; t < 8; ++t) {
      h[t] = f2bf(xv[t]);
      l[t] = f2bf(xv[t] - bf2f(h[t]));
    }
    const int us = (u ^ (row & 7)) * 8;
    *(short8*)&xsh[row][us] = h;
    *(short8*)&xsl[row][us] = l;
  }
  __syncthreads();

  const int ct0 = wv * 3;
  f32x4 acc[3];
#pragma unroll
  for (int i = 0; i < 3; ++i) acc[i] = (f32x4){0.f, 0.f, 0.f, 0.f};
  for (int kc = 0; kc < 32; ++kc) {
    const int us = ((kc * 4 + g) ^ (lr & 7)) * 8;
    const short8 ah = *(const short8*)&xsh[lr][us];
    const short8 al = *(const short8*)&xsl[lr][us];
    const int k0 = kc * 32 + g8;
#pragma unroll
    for (int t = 0; t < 3; ++t) {
      const int ct = ct0 + t;
      const short8 bh = *(const short8*)&wth[(ct * 16 + lr) * CC + k0];
      const short8 bl = *(const short8*)&wtl[(ct * 16 + lr) * CC + k0];
      acc[t] = mfma16(ah, bh, acc[t]);
      acc[t] = mfma16(al, bh, acc[t]);
      acc[t] = mfma16(ah, bl, acc[t]);
    }
  }
#pragma unroll
  for (int t = 0; t < 3; ++t) {
    const int col = ct0 * 16 + t * 16 + lr;
    const int m = col >> 6, d = col & 63;
#pragma unroll
    for (int r = 0; r < 4; ++r) {
      const int row = r0 + g * 4 + r;
      const float val = acc[t][r];
      if (m == 2) {                 // V: no rope; vf + blocked vbb
        vf[row * HD + d] = val;
        const int kp = row >> 5, r32 = row & 31;
        const int gv = r32 >> 3, tv = r32 & 7;
        const int ctv = d >> 4, lrv = d & 15;
        vbb[kp * 2048 + ctv * 512 + gv * 128 + lrv * 8 + tv] = f2bf(val);
      } else {                       // K or Q: rope via table
        const float partner = __shfl_xor(val, 1);
        const int fi = d >> 1;
        const float cs = ctab[row * 32 + fi];
        const float sn = stab[row * 32 + fi];
        const float res = (d & 1) ? (partner * sn + val * cs)
                                  : (val * cs - partner * sn);
        if (m == 0) {
          kf[row * HD + d] = res;
          const int kt = row >> 4, lrk = row & 15;
          const int hh = d >> 5, gk = (d & 31) >> 3, tk = d & 7;
          kbb[kt * 1024 + hh * 512 + gk * 128 + lrk * 8 + tk] = f2bf(res);
        } else {
          qf[row * HD + d] = res;
          qb[row * HD + d] = f2bf(res);
        }
      }
    }
  }
}

// ---- K3: attention, 16 waves/block (1024 thr), grid 512; single-chain,
//          blocked coalesced K/V loads + NT stores --------------------------
__global__ __launch_bounds__(1024) void attn_row(
    const short* __restrict__ qb, const short* __restrict__ kbb,
    const short* __restrict__ vbb, float* __restrict__ colsums,
    float* __restrict__ outp, float* __restrict__ stash,
    float* __restrict__ linv_g) {
  const int tid = threadIdx.x;
  const int lane = tid & 63, wv = tid >> 6;          // wv 0..15
  const int g = lane >> 4, lr = lane & 15, g8 = g * 8;
  const int bid = (int)blockIdx.x;
  const int rt = (bid < 256) ? (511 - bid) : (bid - 256);
  const int r0 = rt * 16, rmax = r0 + 15;
  const int nkt = rt + 1;
  const int nktp = (nkt + 1) >> 1;
  float* imp = outp + IMP_OFF;
  const f32x4 z4 = (f32x4){0.f, 0.f, 0.f, 0.f};

  __shared__ float et[16][16][36];   // 36.9 KB; reused as combine buffer
  __shared__ float l4[16][16];

  const short8 a0 = *(const short8*)&qb[(r0 + lr) * HD + g8];
  const short8 a1 = *(const short8*)&qb[(r0 + lr) * HD + 32 + g8];
  const int ln8 = lane * 8;

  // ---- pass A: denominators, single chain, stride 16 (coalesced kbb)
  float lacc[4] = {0.f, 0.f, 0.f, 0.f};
  for (int kt = wv; kt < nkt; kt += 16) {
    const short8 b0 = *(const short8*)&kbb[kt * 1024 + ln8];
    const short8 b1 = *(const short8*)&kbb[kt * 1024 + 512 + ln8];
    f32x4 sv = z4;
    sv = mfma16(a0, b0, sv);
    sv = mfma16(a1, b1, sv);
    const int j = kt * 16 + lr;
#pragma unroll
    for (int r = 0; r < 4; ++r) {
      const int i = r0 + g * 4 + r;
      if (j <= i) lacc[r] += __expf(sv[r] * 0.125f);
    }
  }
#pragma unroll
  for (int r = 0; r < 4; ++r) {
#pragma unroll
    for (int m = 1; m < 16; m <<= 1) lacc[r] += __shfl_xor(lacc[r], m);
  }
  if (lr == 0) {
#pragma unroll
    for (int r = 0; r < 4; ++r) l4[wv][g * 4 + r] = lacc[r];
  }
  __syncthreads();
  float rinv[4];
#pragma unroll
  for (int r = 0; r < 4; ++r) {
    const int row = g * 4 + r;
    float s = 0.f;
#pragma unroll
    for (int w = 0; w < 16; ++w) s += l4[w][row];
    rinv[r] = 1.0f / s;
  }
  if (wv == 0 && lr == 0) {
#pragma unroll
    for (int r = 0; r < 4; ++r) linv_g[r0 + g * 4 + r] = rinv[r];
  }

  // ---- pass B: single chain, stride 16; wei->imp (NT) + colsums + PV
  f32x4 oacc[4];
#pragma unroll
  for (int ct = 0; ct < 4; ++ct) oacc[ct] = z4;
  const int worow = lane >> 3, wof4 = (lane & 7) * 4;
  for (int kp = wv; kp < nktp; kp += 16) {
    const int j0p = kp * 32;
    short8 bv[4];
#pragma unroll
    for (int ct = 0; ct < 4; ++ct)
      bv[ct] = *(const short8*)&vbb[kp * 2048 + ct * 512 + ln8];
#pragma unroll
    for (int h = 0; h < 2; ++h) {
      const int kt = kp * 2 + h;
      const int j0 = j0p + h * 16;
      float w4[4] = {0.f, 0.f, 0.f, 0.f};
      if (j0 <= rmax) {
        const short8 b0 = *(const short8*)&kbb[kt * 1024 + ln8];
        const short8 b1 = *(const short8*)&kbb[kt * 1024 + 512 + ln8];
        f32x4 sv = z4;
        sv = mfma16(a0, b0, sv);
        sv = mfma16(a1, b1, sv);
        const int j = j0 + lr;
#pragma unroll
        for (int r = 0; r < 4; ++r) {
          const int i = r0 + g * 4 + r;
          w4[r] = (j <= i) ? __expf(sv[r] * 0.125f) * rinv[r] : 0.0f;
        }
        float csum = w4[0] + w4[1] + w4[2] + w4[3];
        csum += __shfl_xor(csum, 16);
        csum += __shfl_xor(csum, 32);
        if (lane < 16 && csum > 0.f) atomicAdd(&colsums[j0 + lane], csum);
      }
#pragma unroll
      for (int r = 0; r < 4; ++r) et[wv][g * 4 + r][h * 16 + lr] = w4[r];
    }
    // PV MFMA from this wave's LDS tile (same-wave ordering: no barrier)
    const float4 e0 = *(const float4*)&et[wv][lr][g8];
    const float4 e1 = *(const float4*)&et[wv][lr][g8 + 4];
    short8 ea;
    ea[0] = f2bf(e0.x); ea[1] = f2bf(e0.y); ea[2] = f2bf(e0.z); ea[3] = f2bf(e0.w);
    ea[4] = f2bf(e1.x); ea[5] = f2bf(e1.y); ea[6] = f2bf(e1.z); ea[7] = f2bf(e1.w);
#pragma unroll
    for (int ct = 0; ct < 4; ++ct) oacc[ct] = mfma16(ea, bv[ct], oacc[ct]);
    // NT coalesced imp write-out from LDS: 16 rows x 32 cols
#pragma unroll
    for (int p = 0; p < 2; ++p) {
      const int row = p * 8 + worow;
      const int i = r0 + row;
      const f32x4 v = *(const f32x4*)&et[wv][row][wof4];
      if (i < TT - 1) nt_store4(&imp[(size_t)i * TT + j0p + wof4], v);
      else            *(f32x4*)&stash[j0p + wof4] = v;
    }
  }
  // zero-fill masked columns [nktp*32, TT) with NT stores
  const int zstart = nktp * 32;
  for (int row = 0; row < 16; ++row) {
    const int i = r0 + row;
    if (i < TT - 1) {
      float* dst = &imp[(size_t)i * TT];
      for (int c = zstart + tid * 4; c < TT; c += 4096) nt_store4(&dst[c], z4);
    } else {
      for (int c = zstart + tid * 4; c < TT; c += 4096) *(f32x4*)&stash[c] = z4;
    }
  }
  // ---- tree-combine 16 waves' PV partials through et (freed after barrier)
  __syncthreads();
  float* cbuf = &et[0][0][0];        // 8 slots x 1024 floats = 32 KB <= et
#pragma unroll
  for (int step = 8; step >= 1; step >>= 1) {
    if (wv >= step && wv < 2 * step) {
      float* dst = cbuf + (size_t)(wv - step) * 1024;
#pragma unroll
      for (int ct = 0; ct < 4; ++ct)
#pragma unroll
        for (int r = 0; r < 4; ++r)
          dst[(g * 4 + r) * 64 + ct * 16 + lr] = oacc[ct][r];
    }
    __syncthreads();
    if (wv < step) {
      const float* src = cbuf + (size_t)wv * 1024;
#pragma unroll
      for (int ct = 0; ct < 4; ++ct)
#pragma unroll
        for (int r = 0; r < 4; ++r)
          oacc[ct][r] += src[(g * 4 + r) * 64 + ct * 16 + lr];
    }
    __syncthreads();
  }
  if (wv == 0) {
#pragma unroll
    for (int ct = 0; ct < 4; ++ct)
#pragma unroll
      for (int r = 0; r < 4; ++r)
        outp[(size_t)(r0 + g * 4 + r) * HD + ct * 16 + lr] = oacc[ct][r];
  }
}

// ---- K4: exact f32 tail rows ------------------------------------------------
__global__ __launch_bounds__(256) void tail_exact(
    const float* __restrict__ qf, const float* __restrict__ kf,
    float* __restrict__ l_exact, float* __restrict__ tail_e) {
  const int b = blockIdx.x;
  const int i = TAIL0 + b;
  const int tid = threadIdx.x;
  __shared__ float qs[64];
  __shared__ float ws4[4];
  if (tid < 64) {
    qs[tid] = qf[i * HD + tid];
    if (TAIL0 + tid > i) tail_e[(b << 6) + tid] = 0.0f;
  }
  __syncthreads();
  float part = 0.f;
  for (int j = tid; j <= i; j += 256) {
    const float* kr = &kf[(size_t)j * HD];
    float dot = 0.f;
#pragma unroll
    for (int d = 0; d < 64; ++d) dot += qs[d] * kr[d];
    const float e = expf(dot * 0.125f);
    part += e;
    if (j >= TAIL0) tail_e[(b << 6) + (j - TAIL0)] = e;
  }
#pragma unroll
  for (int m = 1; m < 64; m <<= 1) part += __shfl_xor(part, m);
  if ((tid & 63) == 0) ws4[tid >> 6] = part;
  __syncthreads();
  if (tid == 0) l_exact[b] = ws4[0] + ws4[1] + ws4[2] + ws4[3];
}

// ---- K5: argmin (exact tail cols, coarse below) ------------------------------
__global__ void argmin_k(const float* __restrict__ colsums,
                         const float* __restrict__ l_exact,
                         const float* __restrict__ tail_e,
                         int* __restrict__ evict) {
  __shared__ float sv[4];
  __shared__ int si[4];
  const int tid = threadIdx.x, lane = tid & 63, wv = tid >> 6;
  float best = 3.4e38f; int bi = TT;
  for (int j = tid; j < TT; j += 256) {
    float v;
    if (j >= TAIL0) {
      const int jc = j - TAIL0;
      v = 0.f;
      for (int b = jc; b < 64; ++b) v += tail_e[(b << 6) + jc] / l_exact[b];
    } else {
      v = colsums[j];
    }
    if (v < best) { best = v; bi = j; }
  }
#pragma unroll
  for (int m = 1; m < 64; m <<= 1) {
    const float ov = __shfl_xor(best, m);
    const int oi = __shfl_xor(bi, m);
    if (ov < best || (ov == best && oi < bi)) { best = ov; bi = oi; }
  }
  if (lane == 0) { sv[wv] = best; si[wv] = bi; }
  __syncthreads();
  if (tid == 0) {
    for (int w = 1; w < 4; ++w)
      if (sv[w] < best || (sv[w] == best && si[w] < bi)) { best = sv[w]; bi = si[w]; }
    evict[0] = bi;
  }
}

// ---- K6: fix rows [eid..TT-2] (recompute/stash) + cache_k/v write -----------
__global__ __launch_bounds__(256) void fix_cache(
    const float* __restrict__ qf, const float* __restrict__ kf,
    const float* __restrict__ vf, const float* __restrict__ linv,
    const float* __restrict__ stash, const int* __restrict__ evict,
    float* __restrict__ outp) {
  const int bid = (int)blockIdx.x;
  const int tid = threadIdx.x;
  const int eid = evict[0];
  if (bid < 512) {
    float* imp = outp + IMP_OFF;
    __shared__ float qs[64];
    for (int dst = eid + bid; dst < TT - 1; dst += 512) {
      const int src = dst + 1;
      if (src == TT - 1) {
        for (int c = tid; c < TT / 4; c += 256)
          ((f32x4*)&imp[(size_t)dst * TT])[c] = ((const f32x4*)stash)[c];
      } else {
        if (tid < 64) qs[tid] = qf[src * HD + tid];
        __syncthreads();
        const float rinv = linv[src];
        for (int j = tid; j < TT; j += 256) {
          float w = 0.f;
          if (j <= src) {
            const float* kr = &kf[(size_t)j * HD];
            float dot = 0.f;
#pragma unroll
            for (int d = 0; d < 64; ++d) dot += qs[d] * kr[d];
            w = expf(dot * 0.125f) * rinv;
          }
          imp[(size_t)dst * TT + j] = w;
        }
        __syncthreads();
      }
    }
  } else {
    const int t = (bid - 512) * 256 + tid;
    const int per = (TT - 1) * (HD / 4);
    if (t >= 2 * per) return;
    const int m = t / per;
    const int rem = t - m * per;
    const int r = rem >> 4, c4 = rem & 15;
    const int src = r + (r >= eid);
    const float* sp = m ? vf : kf;
    const f32x4 val = *(const f32x4*)&sp[src * HD + c4 * 4];
    float* dst = outp + (m ? CV_OFF : CK_OFF);
    nt_store4(&dst[r * HD + c4 * 4], val);
  }
}

extern "C" void kernel_launch(void* const* d_in, const int* in_sizes, int n_in,
                              void* d_out, int out_size, void* d_ws, size_t ws_size,
                              hipStream_t stream) {
  const float* x  = (const float*)d_in[0];
  const float* Wk = (const float*)d_in[1];
  const float* Wq = (const float*)d_in[2];
  const float* Wv = (const float*)d_in[3];
  float* outp = (float*)d_out;
  char* ws = (char*)d_ws;
  short* qb      = (short*)(ws);                        // 1 MB
  short* kbb     = (short*)(ws + (1u << 20));           // 1 MB (blocked K)
  short* vbb     = (short*)(ws + (2u << 20));           // 1 MB (blocked V)
  float* kf      = (float*)(ws + (3u << 20));           // 2 MB
  float* vf      = (float*)(ws + (5u << 20));           // 2 MB
  float* qf      = (float*)(ws + (7u << 20));           // 2 MB
  float* linv    = (float*)(ws + (9u << 20));           // 32 KB
  int*   evict   = (int*)  (ws + (9u << 20) + (64u << 10));   // 4 B
  float* colsums = (float*)(ws + (9u << 20) + (384u << 10));  // 32 KB
  short* wth     = (short*)(ws + (9u << 20) + (448u << 10));  // 384 KB
  short* wtl     = (short*)(ws + (9u << 20) + (832u << 10));  // 384 KB
  float* tail_e  = (float*)(ws + (9u << 20) + (1280u << 10)); // 16 KB
  float* l_exact = (float*)(ws + (9u << 20) + (1344u << 10)); // 256 B
  float* stash   = (float*)(ws + (9u << 20) + (1408u << 10)); // 32 KB
  float* ctab    = (float*)(ws + (12u << 20));          // 1 MB
  float* stab    = (float*)(ws + (13u << 20));          // 1 MB

  prep<<<1824, 256, 0, stream>>>(Wk, Wq, Wv, wth, wtl, colsums, ctab, stab);
  qkv_rope<<<512, 256, 0, stream>>>(x, wth, wtl, ctab, stab, qb, kbb, vbb, kf, vf, qf);
  attn_row<<<512, 1024, 0, stream>>>(qb, kbb, vbb, colsums, outp, stash, linv);
  tail_exact<<<64, 256, 0, stream>>>(qf, kf, l_exact, tail_e);
  argmin_k<<<1, 256, 0, stream>>>(colsums, l_exact, tail_e, evict);
  fix_cache<<<1536, 256, 0, stream>>>(qf, kf, vf, linv, stash, evict, outp);
}